// Round 2
// baseline (120.597 us; speedup 1.0000x reference)
//
#include <hip/hip_runtime.h>
#include <hip/hip_bf16.h>

// Table-batched INT8 embedding-bag (SUM pooling) with per-row scale/bias dequant.
// Shapes fixed by the reference: T=4, E=1e6, D=64, B=8192, L=50 (ragged-safe anyway).
#define T_TABLES 4
#define E_ROWS   1000000
#define D_DIM    64
#define B_BAGS   8192

// One wave per (table, bag). Block = 256 threads = 4 waves = the 4 tables of one
// bag, so the block's 4 output segments are contiguous (1 KiB coalesced store).
__global__ __launch_bounds__(256, 4)
void tbe_fwd_kernel(const int*   __restrict__ qw,     // [T*E*D] int32 holding uint8 values
                    const float* __restrict__ sc,     // [T*E]
                    const float* __restrict__ bs,     // [T*E]
                    const int*   __restrict__ idx,    // [T*B*L]
                    const int*   __restrict__ offs,   // [T*B+1]
                    float*       __restrict__ out)    // [B, T*D] float32
{
    const int lane = threadIdx.x & 63;
    const int t    = threadIdx.x >> 6;   // wave id == table id
    const int b    = blockIdx.x;         // bag id within each table

    const int bag  = t * B_BAGS + b;
    const int off0 = offs[bag];
    const int off1 = offs[bag + 1];

    const unsigned tE = (unsigned)t * (unsigned)E_ROWS;
    const int* __restrict__ qbase = qw + (size_t)tE * D_DIM;

    float acc  = 0.0f;   // lane's dim accumulator (q*s part)
    float bsum = 0.0f;   // per-lane partial of sum-of-biases

    // Ragged-safe chunking (L=50 -> single chunk, n=50).
    for (int base = off0; base < off1; base += 64) {
        const int n = min(64, off1 - base);

        int   myidx = 0;
        float ms    = 0.0f;
        float mb    = 0.0f;
        if (lane < n) {
            myidx = idx[base + lane];                 // coalesced 4B/lane
            ms    = sc[tE + (unsigned)myidx];         // scattered 4B (L2/L3-resident table)
            mb    = bs[tE + (unsigned)myidx];
        }
        bsum += mb;

        int j = 0;
        #define BODY(J) {                                                        \
            const int   r = __shfl(myidx, (J), 64);                              \
            const float s = __shfl(ms,    (J), 64);                              \
            const float q = (float)qbase[(size_t)((unsigned)r) * D_DIM + lane];  \
            acc = fmaf(q, s, acc); }
        for (; j + 4 <= n; j += 4) { BODY(j) BODY(j + 1) BODY(j + 2) BODY(j + 3) }
        for (; j < n; ++j)         { BODY(j) }
        #undef BODY
    }

    // Wave-reduce the bias sum; every dim of the bag gets + sum_j b_j.
    #pragma unroll
    for (int o = 32; o > 0; o >>= 1) bsum += __shfl_xor(bsum, o, 64);
    acc += bsum;

    out[(size_t)b * (T_TABLES * D_DIM) + t * D_DIM + lane] = acc;
}

extern "C" void kernel_launch(void* const* d_in, const int* in_sizes, int n_in,
                              void* d_out, int out_size, void* d_ws, size_t ws_size,
                              hipStream_t stream)
{
    const int*   qw   = (const int*)  d_in[0];
    const float* sc   = (const float*)d_in[1];
    const float* bs   = (const float*)d_in[2];
    const int*   idx  = (const int*)  d_in[3];
    const int*   offs = (const int*)  d_in[4];
    float*       out  = (float*)      d_out;

    dim3 grid(B_BAGS);
    dim3 block(256);
    hipLaunchKernelGGL(tbe_fwd_kernel, grid, block, 0, stream,
                       qw, sc, bs, idx, offs, out);
}

// Round 3
// 120.109 us; speedup vs baseline: 1.0041x; 1.0041x over previous
//
#include <hip/hip_runtime.h>
#include <hip/hip_bf16.h>

// Table-batched INT8 embedding-bag (SUM pooling) with per-row scale/bias dequant.
// T=4, E=1e6, D=64, B=8192, L=50 (ragged-safe).
#define T_TABLES 4
#define E_ROWS   1000000
#define D_DIM    64
#define B_BAGS   8192

// One wave per (table, bag); wave id == table id. Vectorized row gather:
// lane l covers dim-group c = l&15 (dims 4c..4c+3) of row-slot g = l>>4,
// so one int4 load per lane fetches 4 full rows per wave instruction (1 KiB).
__global__ __launch_bounds__(256, 8)
void tbe_fwd_kernel(const int*   __restrict__ qw,     // [T*E*D] int32 holding uint8
                    const float* __restrict__ sc,     // [T*E]
                    const float* __restrict__ bs,     // [T*E]
                    const int*   __restrict__ idx,    // [T*B*L]
                    const int*   __restrict__ offs,   // [T*B+1]
                    float*       __restrict__ out)    // [B, T*D] float32
{
    const int lane = threadIdx.x & 63;
    const int t    = threadIdx.x >> 6;   // wave id == table id
    const int b    = blockIdx.x;         // bag id within each table
    const int g    = lane >> 4;          // row-slot within a 4-row group
    const int c    = lane & 15;          // dim-group (4 dims)

    const int bag  = t * B_BAGS + b;
    const int off0 = offs[bag];
    const int off1 = offs[bag + 1];

    const unsigned tE = (unsigned)t * (unsigned)E_ROWS;
    const int* __restrict__ qbase = qw + (size_t)tE * D_DIM;

    float ax = 0.f, ay = 0.f, az = 0.f, aw = 0.f;  // partial dims 4c..4c+3
    float bsum = 0.f;                               // per-lane bias partial

    for (int base = off0; base < off1; base += 64) {
        const int n = min(64, off1 - base);

        int   myidx = 0;
        float ms    = 0.f;
        float mb    = 0.f;
        if (lane < n) {
            myidx = idx[base + lane];          // coalesced
            ms    = sc[tE + (unsigned)myidx];  // scattered 4B (L2/L3-resident)
            mb    = bs[tE + (unsigned)myidx];
        }
        bsum += mb;

        // 4 rows per body; 4 bodies per iteration -> 4 KiB in flight per wave.
        // Row-slots rl >= n contribute 0 (ms==0 there via the lane<n guard);
        // rl <= 63 always, so shfl sources stay in range.
        #define BODY(J) {                                                         \
            const int   rl = (J) + g;                                             \
            const int   r  = __shfl(myidx, rl, 64);                               \
            const float s  = __shfl(ms,    rl, 64);                               \
            const int4  q  = *reinterpret_cast<const int4*>(                      \
                                 qbase + (((size_t)(unsigned)r) << 6) + (c << 2));\
            ax = fmaf((float)q.x, s, ax);                                         \
            ay = fmaf((float)q.y, s, ay);                                         \
            az = fmaf((float)q.z, s, az);                                         \
            aw = fmaf((float)q.w, s, aw); }

        for (int j = 0; j < n; j += 16) { BODY(j) BODY(j + 4) BODY(j + 8) BODY(j + 12) }
        #undef BODY
    }

    // Reduce the 4 row-slot partials (lanes differing in bits 4..5).
    #pragma unroll
    for (int o = 16; o <= 32; o <<= 1) {
        ax += __shfl_xor(ax, o, 64);
        ay += __shfl_xor(ay, o, 64);
        az += __shfl_xor(az, o, 64);
        aw += __shfl_xor(aw, o, 64);
    }
    // Bias sum across the whole wave; added uniformly to every dim.
    #pragma unroll
    for (int o = 32; o > 0; o >>= 1) bsum += __shfl_xor(bsum, o, 64);

    if (lane < 16) {
        float4 r = { ax + bsum, ay + bsum, az + bsum, aw + bsum };
        *reinterpret_cast<float4*>(out + (size_t)b * (T_TABLES * D_DIM)
                                       + t * D_DIM + (c << 2)) = r;
    }
}

extern "C" void kernel_launch(void* const* d_in, const int* in_sizes, int n_in,
                              void* d_out, int out_size, void* d_ws, size_t ws_size,
                              hipStream_t stream)
{
    const int*   qw   = (const int*)  d_in[0];
    const float* sc   = (const float*)d_in[1];
    const float* bs   = (const float*)d_in[2];
    const int*   idx  = (const int*)  d_in[3];
    const int*   offs = (const int*)  d_in[4];
    float*       out  = (float*)      d_out;

    dim3 grid(B_BAGS);
    dim3 block(256);
    hipLaunchKernelGGL(tbe_fwd_kernel, grid, block, 0, stream,
                       qw, sc, bs, idx, offs, out);
}

// Round 4
// 107.692 us; speedup vs baseline: 1.1198x; 1.1153x over previous
//
#include <hip/hip_runtime.h>
#include <hip/hip_bf16.h>

// Table-batched INT8 embedding-bag (SUM pooling) with per-row scale/bias dequant.
// T=4, E=1e6, D=64, B=8192, L=50 (ragged-safe).
#define T_TABLES 4
#define E_ROWS   1000000
#define D_DIM    64
#define B_BAGS   8192

// Pass 1: pack per-row (scale, bias) into one float2 array in workspace so the
// main kernel's scattered parameter gather touches ONE cache line per lookup
// instead of two (sc[] and bs[] are disjoint arrays -> 2 lines otherwise).
__global__ __launch_bounds__(256)
void pack_params_kernel(const float* __restrict__ sc,
                        const float* __restrict__ bs,
                        float2*      __restrict__ pk,   // [T*E]
                        int n)
{
    int i = blockIdx.x * 256 + threadIdx.x;
    int stride = gridDim.x * 256;
    for (; i < n; i += stride) {
        float2 p;
        p.x = sc[i];
        p.y = bs[i];
        pk[i] = p;
    }
}

// One wave per (table, bag); wave id == table id. Vectorized row gather:
// lane l covers dim-group c = l&15 (dims 4c..4c+3) of row-slot g = l>>4,
// so one int4 load per lane fetches 4 full rows per wave instruction (1 KiB).
__global__ __launch_bounds__(256, 8)
void tbe_fwd_kernel(const int*    __restrict__ qw,     // [T*E*D] int32 holding uint8
                    const float2* __restrict__ pk,     // [T*E] packed (scale, bias)
                    const int*    __restrict__ idx,    // [T*B*L]
                    const int*    __restrict__ offs,   // [T*B+1]
                    float*        __restrict__ out)    // [B, T*D] float32
{
    const int lane = threadIdx.x & 63;
    const int t    = threadIdx.x >> 6;   // wave id == table id
    const int b    = blockIdx.x;         // bag id within each table
    const int g    = lane >> 4;          // row-slot within a 4-row group
    const int c    = lane & 15;          // dim-group (4 dims)

    const int bag  = t * B_BAGS + b;
    const int off0 = offs[bag];
    const int off1 = offs[bag + 1];

    const unsigned tE = (unsigned)t * (unsigned)E_ROWS;
    const int* __restrict__ qbase = qw + (size_t)tE * D_DIM;

    float ax = 0.f, ay = 0.f, az = 0.f, aw = 0.f;  // partial dims 4c..4c+3
    float bsum = 0.f;                               // per-lane bias partial

    for (int base = off0; base < off1; base += 64) {
        const int n = min(64, off1 - base);

        int   myidx = 0;
        float ms    = 0.f;
        if (lane < n) {
            myidx = idx[base + lane];                   // coalesced
            float2 p = pk[tE + (unsigned)myidx];        // ONE scattered 8B line-touch
            ms    = p.x;
            bsum += p.y;
        }

        // 4 rows per body; 4 bodies per iteration -> 4 KiB in flight per wave.
        // Row-slots rl >= n contribute 0 (ms==0 there via the lane<n guard).
        #define BODY(J) {                                                         \
            const int   rl = (J) + g;                                             \
            const int   r  = __shfl(myidx, rl, 64);                               \
            const float s  = __shfl(ms,    rl, 64);                               \
            const int4  q  = *reinterpret_cast<const int4*>(                      \
                                 qbase + (((size_t)(unsigned)r) << 6) + (c << 2));\
            ax = fmaf((float)q.x, s, ax);                                         \
            ay = fmaf((float)q.y, s, ay);                                         \
            az = fmaf((float)q.z, s, az);                                         \
            aw = fmaf((float)q.w, s, aw); }

        for (int j = 0; j < n; j += 16) { BODY(j) BODY(j + 4) BODY(j + 8) BODY(j + 12) }
        #undef BODY
    }

    // Reduce the 4 row-slot partials (lanes differing in bits 4..5).
    #pragma unroll
    for (int o = 16; o <= 32; o <<= 1) {
        ax += __shfl_xor(ax, o, 64);
        ay += __shfl_xor(ay, o, 64);
        az += __shfl_xor(az, o, 64);
        aw += __shfl_xor(aw, o, 64);
    }
    // Bias sum across the whole wave; added uniformly to every dim.
    #pragma unroll
    for (int o = 32; o > 0; o >>= 1) bsum += __shfl_xor(bsum, o, 64);

    if (lane < 16) {
        float4 r = { ax + bsum, ay + bsum, az + bsum, aw + bsum };
        *reinterpret_cast<float4*>(out + (size_t)b * (T_TABLES * D_DIM)
                                       + t * D_DIM + (c << 2)) = r;
    }
}

extern "C" void kernel_launch(void* const* d_in, const int* in_sizes, int n_in,
                              void* d_out, int out_size, void* d_ws, size_t ws_size,
                              hipStream_t stream)
{
    const int*   qw   = (const int*)  d_in[0];
    const float* sc   = (const float*)d_in[1];
    const float* bs   = (const float*)d_in[2];
    const int*   idx  = (const int*)  d_in[3];
    const int*   offs = (const int*)  d_in[4];
    float*       out  = (float*)      d_out;

    float2* pk = (float2*)d_ws;   // 4M * 8 B = 32 MB << ws_size

    const int nparams = T_TABLES * E_ROWS;
    hipLaunchKernelGGL(pack_params_kernel, dim3(2048), dim3(256), 0, stream,
                       sc, bs, pk, nparams);

    hipLaunchKernelGGL(tbe_fwd_kernel, dim3(B_BAGS), dim3(256), 0, stream,
                       qw, pk, idx, offs, out);
}

// Round 5
// 105.584 us; speedup vs baseline: 1.1422x; 1.0200x over previous
//
#include <hip/hip_runtime.h>
#include <hip/hip_fp16.h>

// Table-batched INT8 embedding-bag (SUM pooling) with per-row scale/bias dequant.
// T=4, E=1e6, D=64, B=8192, L=50 (ragged-safe).
#define T_TABLES 4
#define E_ROWS   1000000
#define D_DIM    64
#define B_BAGS   8192

typedef int   v4i __attribute__((ext_vector_type(4)));
typedef float v4f __attribute__((ext_vector_type(4)));

// Pass 1: pack per-row (scale, bias) into ONE half2 (4 B) per row.
// - one scattered line-touch per lookup in the main kernel (vs 2 for sc/bs)
// - 16 MB total footprint -> stays L3-resident even under row-stream pressure
__global__ __launch_bounds__(256)
void pack_params_kernel(const float* __restrict__ sc,
                        const float* __restrict__ bs,
                        __half2*     __restrict__ pk,   // [T*E]
                        int n)
{
    int i = blockIdx.x * 256 + threadIdx.x;
    int stride = gridDim.x * 256;
    for (; i < n; i += stride) {
        float s = __builtin_nontemporal_load(sc + i);   // streamed once
        float b = __builtin_nontemporal_load(bs + i);
        pk[i] = __floats2half2_rn(s, b);                // temporal: reused by gather
    }
}

// One wave per (table, bag); wave id == table id. Vectorized row gather:
// lane l covers dim-group c = l&15 (dims 4c..4c+3) of row-slot g = l>>4,
// so one int4 load per lane fetches 4 full rows per wave instruction (1 KiB).
// Row loads are NON-TEMPORAL: the 419 MB row stream has ~18% reuse but would
// thrash L3 (344 MB distinct > 256 MB), evicting the param table.
__global__ __launch_bounds__(256, 8)
void tbe_fwd_kernel(const int*     __restrict__ qw,     // [T*E*D] int32 holding uint8
                    const __half2* __restrict__ pk,     // [T*E] packed (scale, bias)
                    const int*     __restrict__ idx,    // [T*B*L]
                    const int*     __restrict__ offs,   // [T*B+1]
                    float*         __restrict__ out)    // [B, T*D] float32
{
    const int lane = threadIdx.x & 63;
    const int t    = threadIdx.x >> 6;   // wave id == table id
    const int b    = blockIdx.x;         // bag id within each table
    const int g    = lane >> 4;          // row-slot within a 4-row group
    const int c    = lane & 15;          // dim-group (4 dims)

    const int bag  = t * B_BAGS + b;
    const int off0 = offs[bag];
    const int off1 = offs[bag + 1];

    const unsigned tE = (unsigned)t * (unsigned)E_ROWS;
    const int* __restrict__ qbase = qw + (size_t)tE * D_DIM;

    float ax = 0.f, ay = 0.f, az = 0.f, aw = 0.f;  // partial dims 4c..4c+3
    float bsum = 0.f;                               // per-lane bias partial

    for (int base = off0; base < off1; base += 64) {
        const int n = min(64, off1 - base);

        int   myidx = 0;
        float ms    = 0.f;
        if (lane < n) {
            myidx = __builtin_nontemporal_load(idx + base + lane);  // streamed once
            float2 p = __half22float2(pk[tE + (unsigned)myidx]);    // temporal gather
            ms    = p.x;
            bsum += p.y;
        }

        // 4 rows per body; 4 bodies per iteration -> 4 KiB in flight per wave.
        // Row-slots rl >= n contribute 0 (ms==0 there via the lane<n guard).
        #define BODY(J) {                                                         \
            const int   rl = (J) + g;                                             \
            const int   r  = __shfl(myidx, rl, 64);                               \
            const float s  = __shfl(ms,    rl, 64);                               \
            const v4i   q  = __builtin_nontemporal_load(                          \
                reinterpret_cast<const v4i*>(                                     \
                    qbase + (((size_t)(unsigned)r) << 6) + (c << 2)));            \
            ax = fmaf((float)q[0], s, ax);                                        \
            ay = fmaf((float)q[1], s, ay);                                        \
            az = fmaf((float)q[2], s, az);                                        \
            aw = fmaf((float)q[3], s, aw); }

        for (int j = 0; j < n; j += 16) { BODY(j) BODY(j + 4) BODY(j + 8) BODY(j + 12) }
        #undef BODY
    }

    // Reduce the 4 row-slot partials (lanes differing in bits 4..5).
    #pragma unroll
    for (int o = 16; o <= 32; o <<= 1) {
        ax += __shfl_xor(ax, o, 64);
        ay += __shfl_xor(ay, o, 64);
        az += __shfl_xor(az, o, 64);
        aw += __shfl_xor(aw, o, 64);
    }
    // Bias sum across the whole wave; added uniformly to every dim.
    #pragma unroll
    for (int o = 32; o > 0; o >>= 1) bsum += __shfl_xor(bsum, o, 64);

    if (lane < 16) {
        v4f r = { ax + bsum, ay + bsum, az + bsum, aw + bsum };
        __builtin_nontemporal_store(r,
            reinterpret_cast<v4f*>(out + (size_t)b * (T_TABLES * D_DIM)
                                       + t * D_DIM + (c << 2)));
    }
}

extern "C" void kernel_launch(void* const* d_in, const int* in_sizes, int n_in,
                              void* d_out, int out_size, void* d_ws, size_t ws_size,
                              hipStream_t stream)
{
    const int*   qw   = (const int*)  d_in[0];
    const float* sc   = (const float*)d_in[1];
    const float* bs   = (const float*)d_in[2];
    const int*   idx  = (const int*)  d_in[3];
    const int*   offs = (const int*)  d_in[4];
    float*       out  = (float*)      d_out;

    __half2* pk = (__half2*)d_ws;   // 4M * 4 B = 16 MB << ws_size

    const int nparams = T_TABLES * E_ROWS;
    hipLaunchKernelGGL(pack_params_kernel, dim3(2048), dim3(256), 0, stream,
                       sc, bs, pk, nparams);

    hipLaunchKernelGGL(tbe_fwd_kernel, dim3(B_BAGS), dim3(256), 0, stream,
                       qw, pk, idx, offs, out);
}

// Round 6
// 104.582 us; speedup vs baseline: 1.1531x; 1.0096x over previous
//
#include <hip/hip_runtime.h>
#include <hip/hip_fp16.h>

// Table-batched INT8 embedding-bag (SUM pooling) with per-row scale/bias dequant.
// T=4, E=1e6, D=64, B=8192, L=50 (ragged-safe).
#define T_TABLES 4
#define E_ROWS   1000000
#define D_DIM    64
#define B_BAGS   8192

typedef int   v4i __attribute__((ext_vector_type(4)));
typedef float v4f __attribute__((ext_vector_type(4)));

// Pass 1: pack per-row (scale, bias) into ONE half2 (4 B) per row.
// Per-table slice = 1M * 4 B = 4 MB == one XCD's L2 (see sharding below).
__global__ __launch_bounds__(256)
void pack_params_kernel(const float* __restrict__ sc,
                        const float* __restrict__ bs,
                        __half2*     __restrict__ pk,   // [T*E]
                        int n)
{
    int i = blockIdx.x * 256 + threadIdx.x;
    int stride = gridDim.x * 256;
    for (; i < n; i += stride) {
        float s = __builtin_nontemporal_load(sc + i);   // streamed once
        float b = __builtin_nontemporal_load(bs + i);
        pk[i] = __floats2half2_rn(s, b);
    }
}

// XCD-sharded: blocks round-robin over the 8 XCDs by blockIdx%8 (m09), so
// table t = (bid&7)>>1 pins each table's param gathers to XCD pair {2t,2t+1}.
// Each XCD then re-reads only its own table's 4 MB param slice -> L2-resident,
// killing ~200 MB of repeated L3->L2 fill traffic. One block = 4 waves = 4
// bags of the SAME table. Row loads stay non-temporal (evict-first) so the
// 419 MB row stream doesn't evict the resident params.
__global__ __launch_bounds__(256, 8)
void tbe_fwd_kernel(const int*     __restrict__ qw,     // [T*E*D] int32 holding uint8
                    const __half2* __restrict__ pk,     // [T*E] packed (scale, bias)
                    const int*     __restrict__ idx,    // [T*B*L]
                    const int*     __restrict__ offs,   // [T*B+1]
                    float*         __restrict__ out)    // [B, T*D] float32
{
    const int lane = threadIdx.x & 63;
    const int w    = threadIdx.x >> 6;                 // wave id -> bag-in-quad
    const int bid  = blockIdx.x;                       // [0, 8192)
    const int t    = (bid & 7) >> 1;                   // table, pinned to XCD pair
    const int q    = ((bid >> 3) << 1) | (bid & 1);    // quad index [0, 2048)
    const int b    = q * 4 + w;                        // bag within table [0, 8192)
    const int g    = lane >> 4;                        // row-slot within 4-row group
    const int c    = lane & 15;                        // dim-group (4 dims)

    const int bag  = t * B_BAGS + b;
    const int off0 = offs[bag];
    const int off1 = offs[bag + 1];

    const unsigned tE = (unsigned)t * (unsigned)E_ROWS;
    const int* __restrict__ qbase = qw + (size_t)tE * D_DIM;

    float ax = 0.f, ay = 0.f, az = 0.f, aw = 0.f;  // partial dims 4c..4c+3
    float bsum = 0.f;                               // per-lane bias partial

    for (int base = off0; base < off1; base += 64) {
        const int n = min(64, off1 - base);

        int   myidx = 0;
        float ms    = 0.f;
        if (lane < n) {
            myidx = __builtin_nontemporal_load(idx + base + lane);  // streamed once
            float2 p = __half22float2(pk[tE + (unsigned)myidx]);    // L2-resident gather
            ms    = p.x;
            bsum += p.y;
        }

        // 4 rows per body; 4 bodies in flight -> 4 KiB per wave.
        // Row-slots rl >= n contribute 0 (ms==0 via the lane<n guard).
        #define BODY(J) {                                                         \
            const int   rl = (J) + g;                                             \
            const int   r  = __shfl(myidx, rl, 64);                               \
            const float s  = __shfl(ms,    rl, 64);                               \
            const v4i   qv = __builtin_nontemporal_load(                          \
                reinterpret_cast<const v4i*>(                                     \
                    qbase + (((size_t)(unsigned)r) << 6) + (c << 2)));            \
            ax = fmaf((float)qv[0], s, ax);                                       \
            ay = fmaf((float)qv[1], s, ay);                                       \
            az = fmaf((float)qv[2], s, az);                                       \
            aw = fmaf((float)qv[3], s, aw); }

        for (int j = 0; j < n; j += 16) { BODY(j) BODY(j + 4) BODY(j + 8) BODY(j + 12) }
        #undef BODY
    }

    // Reduce the 4 row-slot partials (lanes differing in bits 4..5).
    #pragma unroll
    for (int o = 16; o <= 32; o <<= 1) {
        ax += __shfl_xor(ax, o, 64);
        ay += __shfl_xor(ay, o, 64);
        az += __shfl_xor(az, o, 64);
        aw += __shfl_xor(aw, o, 64);
    }
    // Bias sum across the whole wave; added uniformly to every dim.
    #pragma unroll
    for (int o = 32; o > 0; o >>= 1) bsum += __shfl_xor(bsum, o, 64);

    if (lane < 16) {
        v4f r = { ax + bsum, ay + bsum, az + bsum, aw + bsum };
        __builtin_nontemporal_store(r,
            reinterpret_cast<v4f*>(out + (size_t)b * (T_TABLES * D_DIM)
                                       + t * D_DIM + (c << 2)));
    }
}

extern "C" void kernel_launch(void* const* d_in, const int* in_sizes, int n_in,
                              void* d_out, int out_size, void* d_ws, size_t ws_size,
                              hipStream_t stream)
{
    const int*   qw   = (const int*)  d_in[0];
    const float* sc   = (const float*)d_in[1];
    const float* bs   = (const float*)d_in[2];
    const int*   idx  = (const int*)  d_in[3];
    const int*   offs = (const int*)  d_in[4];
    float*       out  = (float*)      d_out;

    __half2* pk = (__half2*)d_ws;   // 4M * 4 B = 16 MB << ws_size

    const int nparams = T_TABLES * E_ROWS;
    hipLaunchKernelGGL(pack_params_kernel, dim3(2048), dim3(256), 0, stream,
                       sc, bs, pk, nparams);

    hipLaunchKernelGGL(tbe_fwd_kernel, dim3(8192), dim3(256), 0, stream,
                       qw, pk, idx, offs, out);
}

// Round 7
// 94.517 us; speedup vs baseline: 1.2759x; 1.1065x over previous
//
#include <hip/hip_runtime.h>
#include <hip/hip_fp16.h>

// Table-batched INT8 embedding-bag (SUM pooling) with per-row scale/bias dequant.
// T=4, E=1e6, D=64, B=8192, L=50 (ragged-safe).
#define T_TABLES 4
#define E_ROWS   1000000
#define D_DIM    64
#define B_BAGS   8192

typedef int   v4i __attribute__((ext_vector_type(4)));
typedef float v4f __attribute__((ext_vector_type(4)));

// Pass 1: pack per-row (scale, bias) into ONE half2 (4 B) per row.
// One scattered line-touch per lookup in the main kernel (R4: -12.4 us vs two).
__global__ __launch_bounds__(256)
void pack_params_kernel(const float* __restrict__ sc,
                        const float* __restrict__ bs,
                        __half2*     __restrict__ pk,   // [T*E]
                        int n)
{
    int i = blockIdx.x * 256 + threadIdx.x;
    int stride = gridDim.x * 256;
    for (; i < n; i += stride) {
        float s = __builtin_nontemporal_load(sc + i);   // streamed once
        float b = __builtin_nontemporal_load(bs + i);
        pk[i] = __floats2half2_rn(s, b);
    }
}

// One block = 4 waves = 4 bags of the SAME table; table pinned to an XCD pair
// via bid&7 (neutral but harmless per R6 A/B). Lane l covers dim-group c=l&15
// (dims 4c..4c+3) of row-slot g=l>>4: one int4 load/lane = 4 rows/instr (1 KiB).
// Row loads are TEMPORAL this round: ~18% of lookups are duplicates; letting
// L3 cache rows serves those ~75 MB at L3 rate instead of HBM (R7 A/B vs R6's
// nontemporal rows).
__global__ __launch_bounds__(256, 8)
void tbe_fwd_kernel(const int*     __restrict__ qw,     // [T*E*D] int32 holding uint8
                    const __half2* __restrict__ pk,     // [T*E] packed (scale, bias)
                    const int*     __restrict__ idx,    // [T*B*L]
                    const int*     __restrict__ offs,   // [T*B+1]
                    float*         __restrict__ out)    // [B, T*D] float32
{
    const int lane = threadIdx.x & 63;
    const int w    = threadIdx.x >> 6;                 // wave id -> bag-in-quad
    const int bid  = blockIdx.x;                       // [0, 8192)
    const int t    = (bid & 7) >> 1;                   // table, pinned to XCD pair
    const int q    = ((bid >> 3) << 1) | (bid & 1);    // quad index [0, 2048)
    const int b    = q * 4 + w;                        // bag within table [0, 8192)
    const int g    = lane >> 4;                        // row-slot within 4-row group
    const int c    = lane & 15;                        // dim-group (4 dims)

    const int bag  = t * B_BAGS + b;
    const int off0 = offs[bag];
    const int off1 = offs[bag + 1];

    const unsigned tE = (unsigned)t * (unsigned)E_ROWS;
    const int* __restrict__ qbase = qw + (size_t)tE * D_DIM;

    float ax = 0.f, ay = 0.f, az = 0.f, aw = 0.f;  // partial dims 4c..4c+3
    float bsum = 0.f;                               // per-lane bias partial

    for (int base = off0; base < off1; base += 64) {
        const int n = min(64, off1 - base);

        int   myidx = 0;
        float ms    = 0.f;
        if (lane < n) {
            myidx = __builtin_nontemporal_load(idx + base + lane);  // streamed once
            float2 p = __half22float2(pk[tE + (unsigned)myidx]);    // cached gather
            ms    = p.x;
            bsum += p.y;
        }

        // 4 rows per body; up to 4 bodies in flight -> 4 KiB per wave.
        // Row-slots rl >= n contribute 0 (ms==0 via the lane<n guard).
        #define BODY(J) {                                                         \
            const int   rl = (J) + g;                                             \
            const int   r  = __shfl(myidx, rl, 64);                               \
            const float s  = __shfl(ms,    rl, 64);                               \
            const v4i   qv = *reinterpret_cast<const v4i*>(                       \
                    qbase + (((size_t)(unsigned)r) << 6) + (c << 2));             \
            ax = fmaf((float)qv[0], s, ax);                                       \
            ay = fmaf((float)qv[1], s, ay);                                       \
            az = fmaf((float)qv[2], s, az);                                       \
            aw = fmaf((float)qv[3], s, aw); }

        int j = 0;
        for (; j + 16 <= n; j += 16) { BODY(j) BODY(j + 4) BODY(j + 8) BODY(j + 12) }
        for (; j < n; j += 4)        { BODY(j) }   // tail: <=3 dummy row-slots
        #undef BODY
    }

    // Reduce the 4 row-slot partials (lanes differing in bits 4..5).
    #pragma unroll
    for (int o = 16; o <= 32; o <<= 1) {
        ax += __shfl_xor(ax, o, 64);
        ay += __shfl_xor(ay, o, 64);
        az += __shfl_xor(az, o, 64);
        aw += __shfl_xor(aw, o, 64);
    }
    // Bias sum across the whole wave; added uniformly to every dim.
    #pragma unroll
    for (int o = 32; o > 0; o >>= 1) bsum += __shfl_xor(bsum, o, 64);

    if (lane < 16) {
        v4f r = { ax + bsum, ay + bsum, az + bsum, aw + bsum };
        __builtin_nontemporal_store(r,
            reinterpret_cast<v4f*>(out + (size_t)b * (T_TABLES * D_DIM)
                                       + t * D_DIM + (c << 2)));
    }
}

extern "C" void kernel_launch(void* const* d_in, const int* in_sizes, int n_in,
                              void* d_out, int out_size, void* d_ws, size_t ws_size,
                              hipStream_t stream)
{
    const int*   qw   = (const int*)  d_in[0];
    const float* sc   = (const float*)d_in[1];
    const float* bs   = (const float*)d_in[2];
    const int*   idx  = (const int*)  d_in[3];
    const int*   offs = (const int*)  d_in[4];
    float*       out  = (float*)      d_out;

    __half2* pk = (__half2*)d_ws;   // 4M * 4 B = 16 MB << ws_size

    const int nparams = T_TABLES * E_ROWS;
    hipLaunchKernelGGL(pack_params_kernel, dim3(2048), dim3(256), 0, stream,
                       sc, bs, pk, nparams);

    hipLaunchKernelGGL(tbe_fwd_kernel, dim3(8192), dim3(256), 0, stream,
                       qw, pk, idx, offs, out);
}